// Round 10
// baseline (244.980 us; speedup 1.0000x reference)
//
#include <hip/hip_runtime.h>
#include <hip/hip_bf16.h>
#include <math.h>

typedef __bf16 bf16x2 __attribute__((ext_vector_type(2)));
typedef __bf16 bf16x4 __attribute__((ext_vector_type(4)));
typedef __bf16 bf16x8 __attribute__((ext_vector_type(8)));
typedef float f32x4 __attribute__((ext_vector_type(4)));
typedef float f32x16 __attribute__((ext_vector_type(16)));

#define MFMA16(a, b, c) __builtin_amdgcn_mfma_f32_16x16x32_bf16(a, b, c, 0, 0, 0)
#define MFMA32(a, b, c) __builtin_amdgcn_mfma_f32_32x32x16_bf16(a, b, c, 0, 0, 0)
#define QSCALE 0.1803368801111204f  // 0.125 * log2(e): folded into W's Q-columns

// async global->LDS, 16B/lane, dest = wave-uniform base + lane*16
__device__ __forceinline__ void gload_lds16(const __bf16* g, __bf16* l) {
  __builtin_amdgcn_global_load_lds((const __attribute__((address_space(1))) void*)g,
                                   (__attribute__((address_space(3))) void*)l,
                                   16, 0, 0);
}

// ---------------------------------------------------------------------------
// Kernel 0: convert X fp32 -> bf16
// ---------------------------------------------------------------------------
__global__ __launch_bounds__(256) void convert_x(const float* __restrict__ in,
                                                 __bf16* __restrict__ out) {
  int i = blockIdx.x * 256 + threadIdx.x;
  float4 v = ((const float4*)in)[i];
  bf16x4 o = {(__bf16)v.x, (__bf16)v.y, (__bf16)v.z, (__bf16)v.w};
  *(bf16x4*)&out[i * 4] = o;
}

// ---------------------------------------------------------------------------
// Kernel 1: transpose+convert W fp32 [1024,3072] -> Wt bf16 [3072,1024].
//   Q output-features (bx<16) pre-scaled by 0.125*log2(e).
// ---------------------------------------------------------------------------
__global__ __launch_bounds__(256) void transpose_w(const float* __restrict__ W,
                                                   __bf16* __restrict__ Wt) {
  __shared__ __bf16 tile[64][65];
  const int bx = blockIdx.x;
  const int by = blockIdx.y;
  const int t = threadIdx.x;
  const int lr = t >> 6;
  const int lc = t & 63;
  const float sc = (bx < 16) ? QSCALE : 1.0f;  // block-uniform
#pragma unroll
  for (int i = 0; i < 16; ++i) {
    int r = lr + i * 4;
    tile[r][lc] = (__bf16)(W[(size_t)(by * 64 + r) * 3072 + bx * 64 + lc] * sc);
  }
  __syncthreads();
#pragma unroll
  for (int i = 0; i < 16; ++i) {
    int r = lr + i * 4;
    Wt[(size_t)(bx * 64 + r) * 1024 + by * 64 + lc] = tile[lc][r];
  }
}

// ---------------------------------------------------------------------------
// Kernel 2: QKV = X @ W — COUNTED-VMCNT ring pipeline (T3+T4+T5, m201/m218).
//   BM=256, BN=128, 512 thr (8 waves, 4Mx2N, 64x64/wave). Grid 24x32=768.
//   K is processed in 32 slices of BK=32. 4-slot LDS ring (4 x 24KB = 96KB),
//   3 slices prefetched ahead. Per phase h:
//     STAGE(h+3): 3 gload_lds16/wave (A rows w*32..+31, B rows w*16..+15)
//     s_waitcnt vmcnt(9)   <- slot h's 3 loads retired; 9 stay IN FLIGHT
//     s_barrier            <- slot h resident across all waves
//     ds_read 8 frags; 16 MFMA (setprio)
//     s_barrier            <- all reads of slot h retired before phase h+1
//                             stages into slot (h+4)%4 == h%4
//   Tail h=29,30,31: no stage; vmcnt 6/3/0. NEVER vmcnt(0) in main loop —
//   m218: counted-vs-drain0 = +38..73%. R9's drain-0 version was neutral.
//   Slot layout [row][32] (A 256 rows, then B 128 rows): row stride 64B
//   alternates bank-base 0/16; quad q reads 16B chunk q -> 64 lanes spread
//   8 bank-groups x 8 lanes = the b128 8-cycle floor. No swizzle needed.
//   Epilogues unchanged (verified R9: absmax bit-identical).
// ---------------------------------------------------------------------------
#define GTOT_B 98304  // 4 slots x 12288 elems x 2B

__global__ __launch_bounds__(512, 2) void gemm_qkv(const __bf16* __restrict__ X,
                                                   const __bf16* __restrict__ Wt,
                                                   __bf16* __restrict__ QK,
                                                   __bf16* __restrict__ Vt) {
  extern __shared__ __bf16 lds[];
  const int t = threadIdx.x;
  const int lane = t & 63;
  const int w = t >> 6;
  const int quad = lane >> 4;
  const int l16 = lane & 15;
  const int n0 = blockIdx.x * 128;
  const int m0 = blockIdx.y * 256;
  const int wm = (w >> 1) * 64;  // 4 M-waves
  const int wn = (w & 1) * 64;   // 2 N-waves

  // DMA sources: lane covers row (lane>>2) within the wave's 16-row group,
  // cols (lane&3)*8 .. +8 of the 32-wide K-slice (advances 32/phase).
  const __bf16* As0 = &X[(size_t)(m0 + w * 32 + (lane >> 2)) * 1024 + (lane & 3) * 8];
  const __bf16* As1 = As0 + (size_t)16 * 1024;
  const __bf16* Bsr = &Wt[(size_t)(n0 + w * 16 + (lane >> 2)) * 1024 + (lane & 3) * 8];
  // DMA dests within a slot (elems); DMA adds lane*8 -> row-major [row][32]
  const int dA0 = (w * 32) * 32;
  const int dA1 = (w * 32 + 16) * 32;
  const int dB0 = 8192 + (w * 16) * 32;

  f32x4 acc[4][4] = {};

  auto STAGE = [&](int hh) {
    __bf16* T = lds + (size_t)(hh & 3) * 12288;
    const size_t kc = (size_t)hh * 32;
    gload_lds16(As0 + kc, T + dA0);
    gload_lds16(As1 + kc, T + dA1);
    gload_lds16(Bsr + kc, T + dB0);
  };
  auto COMPUTE = [&](int hh) {
    const __bf16* S = lds + (size_t)(hh & 3) * 12288;
    bf16x8 af[4], bf[4];
#pragma unroll
    for (int mi = 0; mi < 4; ++mi)
      af[mi] = *(const bf16x8*)&S[(wm + mi * 16 + l16) * 32 + quad * 8];
#pragma unroll
    for (int ni = 0; ni < 4; ++ni)
      bf[ni] = *(const bf16x8*)&S[8192 + (wn + ni * 16 + l16) * 32 + quad * 8];
    __builtin_amdgcn_s_setprio(1);
#pragma unroll
    for (int mi = 0; mi < 4; ++mi)
#pragma unroll
      for (int ni = 0; ni < 4; ++ni)
        acc[mi][ni] = MFMA16(af[mi], bf[ni], acc[mi][ni]);
    __builtin_amdgcn_s_setprio(0);
  };

  // ---- prologue: fill 3 slots (9 loads in flight) ----
  STAGE(0);
  STAGE(1);
  STAGE(2);

  // ---- main: phases 0..28, steady-state vmcnt(9) ----
  for (int h = 0; h < 29; ++h) {
    STAGE(h + 3);
    asm volatile("s_waitcnt vmcnt(9)" ::: "memory");
    __builtin_amdgcn_sched_barrier(0);
    __builtin_amdgcn_s_barrier();
    __builtin_amdgcn_sched_barrier(0);
    COMPUTE(h);
    __builtin_amdgcn_sched_barrier(0);
    __builtin_amdgcn_s_barrier();
  }
  // ---- tail: drain 6 -> 3 -> 0 ----
  asm volatile("s_waitcnt vmcnt(6)" ::: "memory");
  __builtin_amdgcn_sched_barrier(0);
  __builtin_amdgcn_s_barrier();
  __builtin_amdgcn_sched_barrier(0);
  COMPUTE(29);
  __builtin_amdgcn_sched_barrier(0);
  __builtin_amdgcn_s_barrier();
  asm volatile("s_waitcnt vmcnt(3)" ::: "memory");
  __builtin_amdgcn_sched_barrier(0);
  __builtin_amdgcn_s_barrier();
  __builtin_amdgcn_sched_barrier(0);
  COMPUTE(30);
  __builtin_amdgcn_sched_barrier(0);
  __builtin_amdgcn_s_barrier();
  asm volatile("s_waitcnt vmcnt(0)" ::: "memory");
  __builtin_amdgcn_sched_barrier(0);
  __builtin_amdgcn_s_barrier();
  __builtin_amdgcn_sched_barrier(0);
  COMPUTE(31);

  if (n0 < 2048) {
    // Q/K epilogue: row-major QK, stride 2048
#pragma unroll
    for (int mi = 0; mi < 4; ++mi)
#pragma unroll
      for (int ni = 0; ni < 4; ++ni)
#pragma unroll
        for (int r = 0; r < 4; ++r) {
          int row = m0 + wm + mi * 16 + quad * 4 + r;
          int col = n0 + wn + ni * 16 + l16;
          QK[(size_t)row * 2048 + col] = (__bf16)acc[mi][ni][r];
        }
  } else {
    // V epilogue: fused transpose into Vt[bh][d][key]; 4 consecutive keys
#pragma unroll
    for (int mi = 0; mi < 4; ++mi)
#pragma unroll
      for (int ni = 0; ni < 4; ++ni) {
        int v = n0 + wn + ni * 16 + l16 - 2048;
        int hh = v >> 6, d = v & 63;
        int row0 = m0 + wm + mi * 16 + quad * 4;
        int bb = row0 >> 11, key = row0 & 2047;
        bf16x4 pk = {(__bf16)acc[mi][ni][0], (__bf16)acc[mi][ni][1],
                     (__bf16)acc[mi][ni][2], (__bf16)acc[mi][ni][3]};
        *(bf16x4*)&Vt[((size_t)(bb * 16 + hh) * 64 + d) * 2048 + key] = pk;
      }
  }
}

// ---------------------------------------------------------------------------
// Kernel 3: flash attention, 32x32x16 MFMA, PERMUTED-K staging + T1 remap.
//   Verified R8/R9: ~86-88 us, FETCH 24.6 MB, 0 bank conflicts. Unchanged.
// ---------------------------------------------------------------------------
#define AT_LD 72  // 144B rows, 16B-aligned

__global__ __launch_bounds__(256) void attn(const __bf16* __restrict__ QK,
                                            const __bf16* __restrict__ Vt,
                                            float* __restrict__ Out) {
  const int t = threadIdx.x;
  const int lane = t & 63;
  const int wave = t >> 6;
  const int l31 = lane & 31;
  const int half = lane >> 5;

  // ---- XCD-aware remap (T1) ----
  const int flat = blockIdx.x + (blockIdx.y << 4) + (blockIdx.z << 8);
  const int xcd = flat & 7;
  const int idx = flat >> 3;
  const int bh = xcd * 8 + (idx >> 4);  // 8 (b,h) panels per XCD
  const int qb = idx & 15;
  const int b = bh >> 4;
  const int h = bh & 15;
  const int q0w = qb * 128 + wave * 32;

  const size_t base = (size_t)b * 2048 * 2048;
  const __bf16* Qb = QK + base + h * 64;
  const __bf16* Kb = QK + base + 1024 + h * 64;
  const __bf16* Vtb = Vt + (size_t)(b * 16 + h) * 64 * 2048;  // [d][key]

  __shared__ __bf16 Ks[64 * AT_LD];  // [perm(key)][d]
  __shared__ __bf16 Vs[64 * AT_LD];  // [d][key]

  // Q as B-operand: lane holds Q[q0w+l31][dc*16 + half*8 + j]  (pre-scaled)
  bf16x8 qf[4];
#pragma unroll
  for (int dc = 0; dc < 4; ++dc)
    qf[dc] = *(const bf16x8*)&Qb[(size_t)(q0w + l31) * 2048 + dc * 16 + half * 8];

  f32x16 o[2] = {};
  float lsum = 0.0f;

  const int srow = t >> 2;      // staging row 0..63
  const int sc = (t & 3) * 16;  // staging col chunk
  // K dest row: swap bits 2<->3 (involution); bits 0,1,4,5 kept
  const int prow = (srow & 51) | ((srow & 4) << 1) | ((srow & 8) >> 1);

  for (int kv0 = 0; kv0 < 2048; kv0 += 64) {
    // ---- stage K (row-permuted) and V ----
    bf16x8 k0v = *(const bf16x8*)&Kb[(size_t)(kv0 + srow) * 2048 + sc];
    bf16x8 k1v = *(const bf16x8*)&Kb[(size_t)(kv0 + srow) * 2048 + sc + 8];
    bf16x8 v0v = *(const bf16x8*)&Vtb[(size_t)srow * 2048 + kv0 + sc];
    bf16x8 v1v = *(const bf16x8*)&Vtb[(size_t)srow * 2048 + kv0 + sc + 8];
    __syncthreads();
    *(bf16x8*)&Ks[prow * AT_LD + sc] = k0v;
    *(bf16x8*)&Ks[prow * AT_LD + sc + 8] = k1v;
    *(bf16x8*)&Vs[srow * AT_LD + sc] = v0v;
    *(bf16x8*)&Vs[srow * AT_LD + sc + 8] = v1v;
    __syncthreads();

    // ---- S^T = K.Q^T per 32-row tile; exp2 directly into A-frag order ----
    bf16x8 pf[4];
#pragma unroll
    for (int kt = 0; kt < 2; ++kt) {
      f32x16 c = {};
#pragma unroll
      for (int dc = 0; dc < 4; ++dc) {
        bf16x8 kf = *(const bf16x8*)&Ks[(kt * 32 + l31) * AT_LD + dc * 16 + half * 8];
        c = MFMA32(kf, qf[dc], c);
      }
#pragma unroll
      for (int kkl = 0; kkl < 2; ++kkl) {
        bf16x8 f;
#pragma unroll
        for (int j = 0; j < 8; ++j) {
          float e = __builtin_amdgcn_exp2f(c[8 * kkl + 4 * (j >> 2) + (j & 3)]);
          lsum += e;
          f[j] = (__bf16)e;
        }
        pf[kt * 2 + kkl] = f;
      }
    }

    // ---- O += P V ----
#pragma unroll
    for (int dt = 0; dt < 2; ++dt)
#pragma unroll
      for (int kk = 0; kk < 4; ++kk) {
        bf16x8 vf = *(const bf16x8*)&Vs[(dt * 32 + l31) * AT_LD + kk * 16 + half * 8];
        o[dt] = MFMA32(pf[kk], vf, o[dt]);
      }
  }

  // ---- denominator: the two halves partition each q's keys ----
  lsum += __shfl_xor(lsum, 32);
  float inv = 1.0f / lsum;  // valid for q == l31

  float iv[16];
#pragma unroll
  for (int r = 0; r < 16; ++r)
    iv[r] = __shfl(inv, (r & 3) + 8 * (r >> 2) + 4 * half);

  // ---- epilogue: O C-layout col=l31=d(+32dt), row=q regmap ----
#pragma unroll
  for (int dt = 0; dt < 2; ++dt)
#pragma unroll
    for (int r = 0; r < 16; ++r) {
      int qr = (r & 3) + 8 * (r >> 2) + 4 * half;
      Out[(size_t)(b * 2048 + q0w + qr) * 1024 + h * 64 + dt * 32 + l31] =
          o[dt][r] * iv[r];
    }
}

// ---------------------------------------------------------------------------
extern "C" void kernel_launch(void* const* d_in, const int* in_sizes, int n_in,
                              void* d_out, int out_size, void* d_ws, size_t ws_size,
                              hipStream_t stream) {
  const float* x = (const float*)d_in[0];        // [4,2048,1024] fp32
  const float* w = (const float*)d_in[1];        // [1024,3072]  fp32
  float* out = (float*)d_out;                    // [4,2048,1024] fp32

  __bf16* Wt = (__bf16*)d_ws;                    // [3072,1024]   6.29 MB
  __bf16* QK = Wt + (size_t)3072 * 1024;         // [8192,2048]  33.55 MB
  __bf16* Xb = QK + (size_t)8192 * 2048;         // [8192,1024]  16.78 MB
  __bf16* Vtr = Xb + (size_t)8192 * 1024;        // [64,64,2048] 16.78 MB

  // one-time: allow 96KB dynamic LDS for gemm_qkv (harmless if redundant)
  static bool attr_done = false;
  if (!attr_done) {
    (void)hipFuncSetAttribute((const void*)gemm_qkv,
                              hipFuncAttributeMaxDynamicSharedMemorySize,
                              GTOT_B);
    attr_done = true;
  }

  convert_x<<<8192, 256, 0, stream>>>(x, Xb);
  transpose_w<<<dim3(48, 16), 256, 0, stream>>>(w, Wt);
  gemm_qkv<<<dim3(24, 32), 512, GTOT_B, stream>>>(Xb, Wt, QK, Vtr);
  attn<<<dim3(16, 16, 4), 256, 0, stream>>>(QK, Vtr, out);
}

// Round 11
// 235.466 us; speedup vs baseline: 1.0404x; 1.0404x over previous
//
#include <hip/hip_runtime.h>
#include <hip/hip_bf16.h>
#include <math.h>

typedef __bf16 bf16x2 __attribute__((ext_vector_type(2)));
typedef __bf16 bf16x4 __attribute__((ext_vector_type(4)));
typedef __bf16 bf16x8 __attribute__((ext_vector_type(8)));
typedef float f32x4 __attribute__((ext_vector_type(4)));
typedef float f32x16 __attribute__((ext_vector_type(16)));

#define MFMA16(a, b, c) __builtin_amdgcn_mfma_f32_16x16x32_bf16(a, b, c, 0, 0, 0)
#define MFMA32(a, b, c) __builtin_amdgcn_mfma_f32_32x32x16_bf16(a, b, c, 0, 0, 0)
#define QSCALE 0.1803368801111204f  // 0.125 * log2(e): folded into W's Q-columns

// async global->LDS, 16B/lane, dest = wave-uniform base + lane*16
__device__ __forceinline__ void gload_lds16(const __bf16* g, __bf16* l) {
  __builtin_amdgcn_global_load_lds((const __attribute__((address_space(1))) void*)g,
                                   (__attribute__((address_space(3))) void*)l,
                                   16, 0, 0);
}

// ---------------------------------------------------------------------------
// Kernel 0: convert X fp32 -> bf16
// ---------------------------------------------------------------------------
__global__ __launch_bounds__(256) void convert_x(const float* __restrict__ in,
                                                 __bf16* __restrict__ out) {
  int i = blockIdx.x * 256 + threadIdx.x;
  float4 v = ((const float4*)in)[i];
  bf16x4 o = {(__bf16)v.x, (__bf16)v.y, (__bf16)v.z, (__bf16)v.w};
  *(bf16x4*)&out[i * 4] = o;
}

// ---------------------------------------------------------------------------
// Kernel 1: transpose+convert W fp32 [1024,3072] -> Wt bf16 [3072,1024].
//   Q output-features (bx<16) pre-scaled by 0.125*log2(e).
// ---------------------------------------------------------------------------
__global__ __launch_bounds__(256) void transpose_w(const float* __restrict__ W,
                                                   __bf16* __restrict__ Wt) {
  __shared__ __bf16 tile[64][65];
  const int bx = blockIdx.x;
  const int by = blockIdx.y;
  const int t = threadIdx.x;
  const int lr = t >> 6;
  const int lc = t & 63;
  const float sc = (bx < 16) ? QSCALE : 1.0f;  // block-uniform
#pragma unroll
  for (int i = 0; i < 16; ++i) {
    int r = lr + i * 4;
    tile[r][lc] = (__bf16)(W[(size_t)(by * 64 + r) * 3072 + bx * 64 + lc] * sc);
  }
  __syncthreads();
#pragma unroll
  for (int i = 0; i < 16; ++i) {
    int r = lr + i * 4;
    Wt[(size_t)(bx * 64 + r) * 1024 + by * 64 + lc] = tile[lc][r];
  }
}

// ---------------------------------------------------------------------------
// Kernel 2: QKV = X @ W. R8-verified structure (128x128 tile, BK=32,
//   global_load_lds w=16, 256 thr, 36KB LDS, ~4 blocks/CU TLP) — both
//   96KB deep-pipeline rewrites (R9 drain-0, R10 counted-vmcnt) regressed
//   +5/+11 us: on this problem block-TLP beats intra-block pipelining.
//   NEW (T1): XCD-aware 4x2 tiling remap. Default dispatch round-robins
//   bx%8 across XCDs -> every XCD touches all 64 A-panels (16MB) vs 4MB L2
//   (A thrashed ~4x). Remap: XCD (mg,ng) owns 16 m-blocks x 12 n-blocks;
//   within, m-inner order keeps the B panel hot and the A strip (4MB = L2)
//   resident. Per-XCD fetch ~= A 4MB + B 3MB.
//     flat = bx + 24*by ; xcd = flat&7 ; i = flat>>3
//     mg = xcd>>1, ng = xcd&1 ; nb = i>>4 (0..11), mb = i&15 (0..15)
//     m0 = (mg*16+mb)*128 ; n0 = (ng*12+nb)*128     (bijective)
//   Q,K columns (n<2048) -> QK row-major; V columns -> Vt fused transpose.
// ---------------------------------------------------------------------------
__global__ __launch_bounds__(256) void gemm_qkv(const __bf16* __restrict__ X,
                                                const __bf16* __restrict__ Wt,
                                                __bf16* __restrict__ QK,
                                                __bf16* __restrict__ Vt) {
  __shared__ __bf16 As[128 * 32];
  __shared__ __bf16 Bs[128 * 32];
  const int t = threadIdx.x;
  const int lane = t & 63;
  const int wave = t >> 6;
  const int quad = lane >> 4;
  const int l16 = lane & 15;

  // ---- XCD-aware 4x2 tiling remap (T1) ----
  const int flat = blockIdx.x + blockIdx.y * 24;
  const int xcd = flat & 7;
  const int i = flat >> 3;       // 0..191 within XCD
  const int mg = xcd >> 1;       // 4 m-groups
  const int ng = xcd & 1;        // 2 n-groups
  const int nb = i >> 4;         // 0..11, outer (B panel hot across 16 mb)
  const int mb = i & 15;         // 0..15, inner
  const int n0 = (ng * 12 + nb) * 128;
  const int m0 = (mg * 16 + mb) * 128;

  const int wm = (wave & 1) * 64;
  const int wn = (wave >> 1) * 64;

  const __bf16* Ag = &X[(size_t)(m0 + wave * 16 + (lane >> 2)) * 1024 + (lane & 3) * 8];
  const __bf16* Bg = &Wt[(size_t)(n0 + wave * 16 + (lane >> 2)) * 1024 + (lane & 3) * 8];
  __bf16* As0 = &As[wave * 512];
  __bf16* As1 = &As[2048 + wave * 512];
  __bf16* Bs0 = &Bs[wave * 512];
  __bf16* Bs1 = &Bs[2048 + wave * 512];

  f32x4 acc[4][4] = {};

  for (int k0 = 0; k0 < 1024; k0 += 32) {
    gload_lds16(Ag + k0, As0);
    gload_lds16(Ag + (size_t)64 * 1024 + k0, As1);
    gload_lds16(Bg + k0, Bs0);
    gload_lds16(Bg + (size_t)64 * 1024 + k0, Bs1);
    __syncthreads();

    bf16x8 af[4], bf[4];
#pragma unroll
    for (int mi = 0; mi < 4; ++mi)
      af[mi] = *(const bf16x8*)&As[(wm + mi * 16 + l16) * 32 + quad * 8];
#pragma unroll
    for (int ni = 0; ni < 4; ++ni)
      bf[ni] = *(const bf16x8*)&Bs[(wn + ni * 16 + l16) * 32 + quad * 8];
#pragma unroll
    for (int mi = 0; mi < 4; ++mi)
#pragma unroll
      for (int ni = 0; ni < 4; ++ni)
        acc[mi][ni] = MFMA16(af[mi], bf[ni], acc[mi][ni]);
    __syncthreads();
  }

  if (n0 < 2048) {
    // Q/K epilogue: row-major QK, stride 2048
#pragma unroll
    for (int mi = 0; mi < 4; ++mi)
#pragma unroll
      for (int ni = 0; ni < 4; ++ni)
#pragma unroll
        for (int r = 0; r < 4; ++r) {
          int row = m0 + wm + mi * 16 + quad * 4 + r;
          int col = n0 + wn + ni * 16 + l16;
          QK[(size_t)row * 2048 + col] = (__bf16)acc[mi][ni][r];
        }
  } else {
    // V epilogue: fused transpose into Vt[bh][d][key]; 4 consecutive keys
#pragma unroll
    for (int mi = 0; mi < 4; ++mi)
#pragma unroll
      for (int ni = 0; ni < 4; ++ni) {
        int v = n0 + wn + ni * 16 + l16 - 2048;
        int hh = v >> 6, d = v & 63;
        int row0 = m0 + wm + mi * 16 + quad * 4;
        int bb = row0 >> 11, key = row0 & 2047;
        bf16x4 pk = {(__bf16)acc[mi][ni][0], (__bf16)acc[mi][ni][1],
                     (__bf16)acc[mi][ni][2], (__bf16)acc[mi][ni][3]};
        *(bf16x4*)&Vt[((size_t)(bb * 16 + hh) * 64 + d) * 2048 + key] = pk;
      }
  }
}

// ---------------------------------------------------------------------------
// Kernel 3: flash attention, 32x32x16 MFMA, PERMUTED-K staging + T1 remap.
//   Verified R8-R10: ~86-88 us, FETCH 24.6 MB, 0 bank conflicts. Unchanged.
// ---------------------------------------------------------------------------
#define AT_LD 72  // 144B rows, 16B-aligned

__global__ __launch_bounds__(256) void attn(const __bf16* __restrict__ QK,
                                            const __bf16* __restrict__ Vt,
                                            float* __restrict__ Out) {
  const int t = threadIdx.x;
  const int lane = t & 63;
  const int wave = t >> 6;
  const int l31 = lane & 31;
  const int half = lane >> 5;

  // ---- XCD-aware remap (T1) ----
  const int flat = blockIdx.x + (blockIdx.y << 4) + (blockIdx.z << 8);
  const int xcd = flat & 7;
  const int idx = flat >> 3;
  const int bh = xcd * 8 + (idx >> 4);  // 8 (b,h) panels per XCD
  const int qb = idx & 15;
  const int b = bh >> 4;
  const int h = bh & 15;
  const int q0w = qb * 128 + wave * 32;

  const size_t base = (size_t)b * 2048 * 2048;
  const __bf16* Qb = QK + base + h * 64;
  const __bf16* Kb = QK + base + 1024 + h * 64;
  const __bf16* Vtb = Vt + (size_t)(b * 16 + h) * 64 * 2048;  // [d][key]

  __shared__ __bf16 Ks[64 * AT_LD];  // [perm(key)][d]
  __shared__ __bf16 Vs[64 * AT_LD];  // [d][key]

  // Q as B-operand: lane holds Q[q0w+l31][dc*16 + half*8 + j]  (pre-scaled)
  bf16x8 qf[4];
#pragma unroll
  for (int dc = 0; dc < 4; ++dc)
    qf[dc] = *(const bf16x8*)&Qb[(size_t)(q0w + l31) * 2048 + dc * 16 + half * 8];

  f32x16 o[2] = {};
  float lsum = 0.0f;

  const int srow = t >> 2;      // staging row 0..63
  const int sc = (t & 3) * 16;  // staging col chunk
  // K dest row: swap bits 2<->3 (involution); bits 0,1,4,5 kept
  const int prow = (srow & 51) | ((srow & 4) << 1) | ((srow & 8) >> 1);

  for (int kv0 = 0; kv0 < 2048; kv0 += 64) {
    // ---- stage K (row-permuted) and V ----
    bf16x8 k0v = *(const bf16x8*)&Kb[(size_t)(kv0 + srow) * 2048 + sc];
    bf16x8 k1v = *(const bf16x8*)&Kb[(size_t)(kv0 + srow) * 2048 + sc + 8];
    bf16x8 v0v = *(const bf16x8*)&Vtb[(size_t)srow * 2048 + kv0 + sc];
    bf16x8 v1v = *(const bf16x8*)&Vtb[(size_t)srow * 2048 + kv0 + sc + 8];
    __syncthreads();
    *(bf16x8*)&Ks[prow * AT_LD + sc] = k0v;
    *(bf16x8*)&Ks[prow * AT_LD + sc + 8] = k1v;
    *(bf16x8*)&Vs[srow * AT_LD + sc] = v0v;
    *(bf16x8*)&Vs[srow * AT_LD + sc + 8] = v1v;
    __syncthreads();

    // ---- S^T = K.Q^T per 32-row tile; exp2 directly into A-frag order ----
    bf16x8 pf[4];
#pragma unroll
    for (int kt = 0; kt < 2; ++kt) {
      f32x16 c = {};
#pragma unroll
      for (int dc = 0; dc < 4; ++dc) {
        bf16x8 kf = *(const bf16x8*)&Ks[(kt * 32 + l31) * AT_LD + dc * 16 + half * 8];
        c = MFMA32(kf, qf[dc], c);
      }
#pragma unroll
      for (int kkl = 0; kkl < 2; ++kkl) {
        bf16x8 f;
#pragma unroll
        for (int j = 0; j < 8; ++j) {
          float e = __builtin_amdgcn_exp2f(c[8 * kkl + 4 * (j >> 2) + (j & 3)]);
          lsum += e;
          f[j] = (__bf16)e;
        }
        pf[kt * 2 + kkl] = f;
      }
    }

    // ---- O += P V ----
#pragma unroll
    for (int dt = 0; dt < 2; ++dt)
#pragma unroll
      for (int kk = 0; kk < 4; ++kk) {
        bf16x8 vf = *(const bf16x8*)&Vs[(dt * 32 + l31) * AT_LD + kk * 16 + half * 8];
        o[dt] = MFMA32(pf[kk], vf, o[dt]);
      }
  }

  // ---- denominator: the two halves partition each q's keys ----
  lsum += __shfl_xor(lsum, 32);
  float inv = 1.0f / lsum;  // valid for q == l31

  float iv[16];
#pragma unroll
  for (int r = 0; r < 16; ++r)
    iv[r] = __shfl(inv, (r & 3) + 8 * (r >> 2) + 4 * half);

  // ---- epilogue: O C-layout col=l31=d(+32dt), row=q regmap ----
#pragma unroll
  for (int dt = 0; dt < 2; ++dt)
#pragma unroll
    for (int r = 0; r < 16; ++r) {
      int qr = (r & 3) + 8 * (r >> 2) + 4 * half;
      Out[(size_t)(b * 2048 + q0w + qr) * 1024 + h * 64 + dt * 32 + l31] =
          o[dt][r] * iv[r];
    }
}

// ---------------------------------------------------------------------------
extern "C" void kernel_launch(void* const* d_in, const int* in_sizes, int n_in,
                              void* d_out, int out_size, void* d_ws, size_t ws_size,
                              hipStream_t stream) {
  const float* x = (const float*)d_in[0];        // [4,2048,1024] fp32
  const float* w = (const float*)d_in[1];        // [1024,3072]  fp32
  float* out = (float*)d_out;                    // [4,2048,1024] fp32

  __bf16* Wt = (__bf16*)d_ws;                    // [3072,1024]   6.29 MB
  __bf16* QK = Wt + (size_t)3072 * 1024;         // [8192,2048]  33.55 MB
  __bf16* Xb = QK + (size_t)8192 * 2048;         // [8192,1024]  16.78 MB
  __bf16* Vtr = Xb + (size_t)8192 * 1024;        // [64,64,2048] 16.78 MB

  convert_x<<<8192, 256, 0, stream>>>(x, Xb);
  transpose_w<<<dim3(48, 16), 256, 0, stream>>>(w, Wt);
  gemm_qkv<<<dim3(24, 64), 256, 0, stream>>>(Xb, Wt, QK, Vtr);
  attn<<<dim3(16, 16, 4), 256, 0, stream>>>(QK, Vtr, out);
}